// Round 26
// baseline (57.489 us; speedup 1.0000x reference)
//
#include <hip/hip_runtime.h>
#include <hip/hip_bf16.h>
#include <math.h>

typedef __hip_bfloat16 bf16;
typedef __attribute__((ext_vector_type(4))) float f32x4;
typedef __attribute__((ext_vector_type(8))) short s16x8;
typedef __attribute__((ext_vector_type(4))) short s16x4;

#define B_     2
#define DIM_   512
#define Hh     48
#define Ww     48
#define T_     2304
#define HEADS_ 8
#define HD_    64
#define NS_    7
#define R_     3
#define KK_    49

typedef __attribute__((address_space(3))) unsigned       lds_u32_t;
typedef __attribute__((address_space(1))) const unsigned glb_u32_t;

// direct global->LDS DMA, 16B per lane (wave-uniform LDS base + lane*16).
__device__ __forceinline__ void gload16(const short* g, short* l) {
    __builtin_amdgcn_global_load_lds((glb_u32_t*)g, (lds_u32_t*)l, 16, 0, 0);
}

__device__ __forceinline__ short f2bs(float f) {
    bf16 h = __float2bfloat16(f);
    return *(short*)&h;
}

__device__ __forceinline__ float bs2f(short s) {
    bf16 h = *reinterpret_cast<const bf16*>(&s);
    return __bfloat162float(h);
}

// load 8 contiguous fp32, convert to 8 bf16 (as shorts)
__device__ __forceinline__ s16x8 cvt8(const float* __restrict__ p) {
    f32x4 a = *(const f32x4*)p;
    f32x4 b = *(const f32x4*)(p + 4);
    s16x8 r;
    r[0] = f2bs(a[0]); r[1] = f2bs(a[1]); r[2] = f2bs(a[2]); r[3] = f2bs(a[3]);
    r[4] = f2bs(b[0]); r[5] = f2bs(b[1]); r[6] = f2bs(b[2]); r[7] = f2bs(b[3]);
    return r;
}

// ---------------------------------------------------------------------------
// prep: fused weight-convert + X transpose-convert (validated, unchanged).
// ---------------------------------------------------------------------------
__global__ __launch_bounds__(256) void prep(
    const float* __restrict__ x,
    const float* __restrict__ wq, const float* __restrict__ wk,
    const float* __restrict__ wv, const float* __restrict__ wo,
    bf16* __restrict__ xt, bf16* __restrict__ wb)
{
    __shared__ short tile[64 * 72];   // [t][c]
    const int gid = blockIdx.x;
    const int tid = threadIdx.x;

    if (gid < 512) {
        const int i     = gid * 256 + tid;
        const int which = i >> 15;
        const int off   = (i & 32767) * 8;
        const float* src = (which == 0) ? wq : (which == 1) ? wk
                         : (which == 2) ? wv : wo;
        *(s16x8*)((short*)wb + which * 262144 + off) = cvt8(src + off);
        return;
    }

    const int pid = gid - 512;
    const int b   = pid / 288;
    const int rem = pid - b * 288;
    const int t0  = (rem % 36) * 64;
    const int c0  = (rem / 36) * 64;

    const float* X = x + (size_t)b * DIM_ * T_;

    const int c_l = tid >> 4;          // 0..15
    const int t4  = (tid & 15) * 4;    // 0..60
#pragma unroll
    for (int cp = 0; cp < 4; ++cp) {
        const int c = cp * 16 + c_l;
        f32x4 v = *(const f32x4*)(X + (size_t)(c0 + c) * T_ + t0 + t4);
#pragma unroll
        for (int e = 0; e < 4; ++e) tile[(t4 + e) * 72 + c] = f2bs(v[e]);
    }
    __syncthreads();

    const int t_l = tid >> 2;           // 0..63
    const int c16 = (tid & 3) * 16;     // 0,16,32,48
    short* dst = (short*)xt + ((size_t)b * T_ + t0 + t_l) * DIM_ + c0 + c16;
    *(s16x8*)(dst)     = *(const s16x8*)(&tile[t_l * 72 + c16]);
    *(s16x8*)(dst + 8) = *(const s16x8*)(&tile[t_l * 72 + c16 + 8]);
}

// ---------------------------------------------------------------------------
// QKV projection GEMM (r25 measured-best, UNCHANGED): 128x128 tile,
// global_load_lds + XOR-swizzle staging, BK-128 unroll (4 drains). LDS 64KB.
// ---------------------------------------------------------------------------
__global__ __launch_bounds__(256) void gemm_qkv(
    const bf16* __restrict__ xt, const bf16* __restrict__ wb,
    const float* __restrict__ bq, const float* __restrict__ bk,
    const float* __restrict__ bv,
    bf16* __restrict__ qb2, bf16* __restrict__ kb2, bf16* __restrict__ vb2)
{
    const int tt   = blockIdx.x * 128;
    const int ot   = blockIdx.y * 128;          // [0,1536)
    const int b    = blockIdx.z;
    const int proj = ot >> 9;
    const int orow = ot & 511;                  // {0,128,256,384}
    const int h0   = orow >> 6;                 // head base {0,2,4,6}

    const float* bsel = (proj == 0) ? bq : (proj == 1) ? bk : bv;
    const short* Wb   = (const short*)wb + proj * 262144;
    const short* X    = (const short*)xt + (size_t)b * T_ * DIM_;
    short*       sel  = (short*)((proj == 0) ? qb2 : (proj == 1) ? kb2 : vb2);

    __shared__ __align__(16) short Xs[4][128 * 32];   // 4 k-substeps x 8 KB
    __shared__ __align__(16) short Ws[4][128 * 32];

    const int tid  = threadIdx.x;
    const int lane = tid & 63;
    const int wid  = tid >> 6;
    const int ln   = lane & 15;
    const int qq   = lane >> 4;

    const int swz8 = (((lane & 3) ^ ((lane >> 3) & 3)) * 8);  // write-side
    const int rsw  = (ln >> 1) & 3;                           // read-side XOR

    f32x4 acc[2][8];
#pragma unroll
    for (int r = 0; r < 2; ++r)
#pragma unroll
        for (int n = 0; n < 8; ++n) acc[r][n] = (f32x4){0.f, 0.f, 0.f, 0.f};

    for (int kk = 0; kk < DIM_; kk += 128) {
#pragma unroll
        for (int s = 0; s < 4; ++s) {
#pragma unroll
            for (int half = 0; half < 2; ++half) {
                const int r0 = wid * 32 + half * 16;       // wave-uniform
                const int r  = r0 + (lane >> 2);
                gload16(X  + (size_t)(tt   + r) * DIM_ + kk + s * 32 + swz8, &Xs[s][r0 * 32]);
                gload16(Wb + (size_t)(orow + r) * DIM_ + kk + s * 32 + swz8, &Ws[s][r0 * 32]);
            }
        }
        __syncthreads();

#pragma unroll
        for (int s = 0; s < 4; ++s) {
            s16x8 a[2];
#pragma unroll
            for (int r = 0; r < 2; ++r) {
                const int rr = r * 64 + wid * 16 + ln;
                a[r] = *(const s16x8*)&Xs[s][rr * 32 + ((qq ^ rsw) * 8)];
            }
#pragma unroll
            for (int n = 0; n < 8; ++n) {
                const int rw = n * 16 + ln;
                s16x8 bf = *(const s16x8*)&Ws[s][rw * 32 + ((qq ^ rsw) * 8)];
#pragma unroll
                for (int r = 0; r < 2; ++r)
                    acc[r][n] = __builtin_amdgcn_mfma_f32_16x16x32_bf16(a[r], bf, acc[r][n], 0, 0, 0);
            }
        }
        __syncthreads();
    }

    const size_t tb = (size_t)(b * HEADS_ + h0);
#pragma unroll
    for (int r = 0; r < 2; ++r)
#pragma unroll
        for (int n = 0; n < 8; ++n) {
            const int hn   = n >> 2;
            const int d    = (n & 3) * 16 + ln;
            const float bi = bsel[orow + n * 16 + ln];
#pragma unroll
            for (int e = 0; e < 4; ++e) {
                const int t = tt + r * 64 + wid * 16 + (lane >> 4) * 4 + e;
                sel[((tb + hn) * T_ + t) * HD_ + d] = f2bs(acc[r][n][e] + bi);
            }
        }
}

// ---------------------------------------------------------------------------
// Output projection GEMM: 64x64 tile, 576 blocks, global_load_lds +
// XOR-swizzle staging, BK-256 unroll: EIGHT sub-tiles per barrier pair
// (2 drains total). LDS 64KB -> cap 2 blocks/CU (offered 2.25).
// ---------------------------------------------------------------------------
__global__ __launch_bounds__(256) void gemm_out(
    const bf16* __restrict__ ao, const bf16* __restrict__ wb,
    const float* __restrict__ bo, float* __restrict__ out)
{
    const int tt = blockIdx.x * 64;
    const int ot = blockIdx.y * 64;
    const int b  = blockIdx.z;

    const short* X  = (const short*)ao + (size_t)b * T_ * DIM_;
    const short* Wb = (const short*)wb + 3 * 262144;

    __shared__ __align__(16) short Ws[8][64 * 32];   // 8 x 4 KB
    __shared__ __align__(16) short Xs[8][64 * 32];   // 8 x 4 KB

    const int tid  = threadIdx.x;
    const int lane = tid & 63;
    const int wid  = tid >> 6;
    const int ln   = lane & 15;
    const int qq   = lane >> 4;

    const int swz8 = (((lane & 3) ^ ((lane >> 3) & 3)) * 8);
    const int rsw  = (ln >> 1) & 3;

    f32x4 acc[4];
#pragma unroll
    for (int n = 0; n < 4; ++n) acc[n] = (f32x4){0.f, 0.f, 0.f, 0.f};

    for (int kk = 0; kk < DIM_; kk += 256) {
#pragma unroll
        for (int s = 0; s < 8; ++s) {
            const int r0 = wid * 16;                  // wave-uniform
            const int r  = r0 + (lane >> 2);
            gload16(Wb + (size_t)(ot + r) * DIM_ + kk + s * 32 + swz8, &Ws[s][r0 * 32]);
            gload16(X  + (size_t)(tt + r) * DIM_ + kk + s * 32 + swz8, &Xs[s][r0 * 32]);
        }
        __syncthreads();

#pragma unroll
        for (int s = 0; s < 8; ++s) {
            s16x8 a = *(const s16x8*)&Ws[s][(wid * 16 + ln) * 32 + ((qq ^ rsw) * 8)];
#pragma unroll
            for (int n = 0; n < 4; ++n) {
                s16x8 bf = *(const s16x8*)&Xs[s][(n * 16 + ln) * 32 + ((qq ^ rsw) * 8)];
                acc[n] = __builtin_amdgcn_mfma_f32_16x16x32_bf16(a, bf, acc[n], 0, 0, 0);
            }
        }
        __syncthreads();
    }

    float* obase = out + (size_t)b * DIM_ * T_;
#pragma unroll
    for (int n = 0; n < 4; ++n) {
        const int t = tt + n * 16 + ln;
#pragma unroll
        for (int e = 0; e < 4; ++e) {
            const int o    = ot + wid * 16 + (lane >> 4) * 4 + e;
            obase[(size_t)o * T_ + t] = acc[n][e] + bo[o];
        }
    }
}

// ---------------------------------------------------------------------------
// MFMA neighborhood attention (measured-best, UNCHANGED): K via
// global_load_lds into unpadded [176][64] Kl with XOR chunk swizzle; Q in
// registers; V reg-staged (T14); T5 setprio; private Ol (4 barriers).
// LDS 36608B, (256,4). grid: 2304 blocks of 256, XCD-swizzled.
// ---------------------------------------------------------------------------
__global__ __launch_bounds__(256, 4) void attn_mfma(
    const bf16* __restrict__ qb2, const bf16* __restrict__ kb2,
    const bf16* __restrict__ vb2, bf16* __restrict__ ao)
{
    __shared__ __align__(16) char smem[36608];
    short* Kl = (short*)smem;                 // [176][64] (stage 0..167)
    short* VT = (short*)smem;                 // [64][200] alias (PV phase)
    short* Pl = (short*)(smem + 25600);       // [16][200]       (private)
    float* Ol = (float*)(smem + 32000);       // [16][72]        (private)

    const int l   = blockIdx.x;
    const int idx = (l & 7) * 288 + (l >> 3);            // XCD-contiguous work
    const int bh  = idx / 144;
    const int rem = idx - bh * 144;
    const int y   = rem / 3;
    const int x0  = (rem % 3) * 16;

    const short* qb  = (const short*)qb2 + (size_t)bh * T_ * HD_;
    const short* kb  = (const short*)kb2 + (size_t)bh * T_ * HD_;
    const short* vbb = (const short*)vb2 + (size_t)bh * T_ * HD_;

    const int tid  = threadIdx.x;
    const int lane = tid & 63;
    const int wv   = tid >> 6;
    const int qq   = lane >> 4;
    const int ln   = lane & 15;

    // ---- zero Pl pads: w in [176,192) (private region, safe pre-bar1) ----
    if (tid < 32) {
        const int t = tid >> 1, c = tid & 1;
        *(s16x8*)&Pl[t * 200 + 176 + c * 8] = (s16x8){0,0,0,0,0,0,0,0};
    }
    // ---- stage K rows via gload16: group g = p*4+wv, rows g*8..g*8+7 ----
    {
        const int swc = (((lane & 7) ^ (lane >> 3)) & 7) * 8;  // global chunk
#pragma unroll
        for (int p = 0; p < 6; ++p) {
            const int g = p * 4 + wv;            // wave-uniform
            if (g < 21) {
                const int r  = g * 8 + (lane >> 3);
                const int wy = r / 24, u = r - wy * 24;
                const int gy = min(max(y + wy - 3, 0), 47);
                const int gx = min(max(x0 + u - 3, 0), 47);
                gload16(kb + (size_t)(gy * 48 + gx) * 64 + swc, &Kl[g * 8 * 64]);
            }
        }
    }
    // ---- Q fragments direct to registers (bitwise = old Ql content) ----
    s16x8 qreg0, qreg1;
    {
        const short* qp = qb + (size_t)(y * 48 + x0 + ln) * 64 + qq * 8;
        qreg0 = *(const s16x8*)(qp);
        qreg1 = *(const s16x8*)(qp + 32);
    }
    // ---- issue V loads to regs (T14: write to LDS after bar2) ----
    s16x4 vreg[10];
    {
        const int rr0 = tid >> 4;          // 0..15
        const int d4  = (tid & 15) * 4;
#pragma unroll
        for (int p = 0; p < 10; ++p) {
            const int rr = p * 16 + rr0;
            if (rr < 154) {
                const int wy = rr / 22, u = rr - wy * 22;
                const int gy = min(max(y + wy - 3, 0), 47);
                const int gx = min(max(x0 + u - 3, 0), 47);
                vreg[p] = *(const s16x4*)(vbb + (size_t)(gy * 48 + gx) * 64 + d4);
            }
        }
    }
    __syncthreads();   // bar1: Kl ready (drains gload_lds via vmcnt)

    // ---- S^T = K x Q^T: 11 m-tiles, 2 k-steps; ALL waves compute all ----
    f32x4 acc[11];
#pragma unroll
    for (int mt = 0; mt < 11; ++mt) acc[mt] = (f32x4){0.f, 0.f, 0.f, 0.f};
    __builtin_amdgcn_s_setprio(1);
#pragma unroll
    for (int ks = 0; ks < 2; ++ks) {
        s16x8 bq_ = (ks == 0) ? qreg0 : qreg1;
#pragma unroll
        for (int mt = 0; mt < 11; ++mt) {
            const int rr = mt * 16 + ln;
            s16x8 ak = *(const s16x8*)&Kl[rr * 64 + (((ks * 4 + qq) ^ (ln & 7)) * 8)];
            acc[mt] = __builtin_amdgcn_mfma_f32_16x16x32_bf16(ak, bq_, acc[mt], 0, 0, 0);
        }
    }
    __builtin_amdgcn_s_setprio(0);

    // ---- mask + wave-local softmax (t = ln; w = mt*16 + qq*4 + e) ----
    const int dx = ln;
    float mxv = -3.0e38f;
#pragma unroll
    for (int mt = 0; mt < 11; ++mt) {
#pragma unroll
        for (int e = 0; e < 4; ++e) {
            const int w  = mt * 16 + qq * 4 + e;
            const int wy = w / 24, u = w - wy * 24;
            const bool valid = (w < 168) &&
                               ((unsigned)(u - dx) <= 6u) &&
                               ((unsigned)(y + wy - 3) < 48u) &&
                               ((unsigned)(x0 + u - 3) < 48u);
            const float s = valid ? acc[mt][e] * 0.125f : -3.0e38f;
            acc[mt][e] = s;
            mxv = fmaxf(mxv, s);
        }
    }
    mxv = fmaxf(mxv, __shfl_xor(mxv, 16));
    mxv = fmaxf(mxv, __shfl_xor(mxv, 32));
    float sum = 0.f;
#pragma unroll
    for (int mt = 0; mt < 11; ++mt)
#pragma unroll
        for (int e = 0; e < 4; ++e) {
            const float p = __expf(acc[mt][e] - mxv);
            acc[mt][e] = p;
            sum += p;
        }
    sum += __shfl_xor(sum, 16);
    sum += __shfl_xor(sum, 32);
    const float inv = 1.0f / sum;

    // ---- write P: compile-time mt, wave-uniform owner (Pl private) ----
#pragma unroll
    for (int mt = 0; mt < 11; ++mt) {
        const int owner = (mt >= 9) ? 3 : (mt / 3);
        if (wv == owner) {
#pragma unroll
            for (int e = 0; e < 4; ++e) {
                const int w = mt * 16 + qq * 4 + e;
                Pl[ln * 200 + w] = f2bs(acc[mt][e] * inv);
            }
        }
    }
    __syncthreads();   // bar2: all Kl reads done -> VT may overwrite

    // ---- zero VT pads + write VT from regs (validated layout) ----
    {
        const int d = tid >> 2, c = tid & 3;
        *(s16x8*)&VT[d * 200 + 168 + c * 8] = (s16x8){0,0,0,0,0,0,0,0};
    }
#pragma unroll
    for (int pp = 0; pp < 2; ++pp) {
        const int r2 = pp * 256 + tid;
        if (r2 < 448) {
            const int wy = r2 >> 6, d = r2 & 63;
            *(unsigned*)&VT[d * 200 + wy * 24 + 22] = 0u;
        }
    }
    {
        const int rr0 = tid >> 4;
        const int d4  = (tid & 15) * 4;
        const int rot = tid & 3;
#pragma unroll
        for (int p = 0; p < 10; ++p) {
            const int rr = p * 16 + rr0;
            if (rr < 154) {
                const int wy = rr / 22, u = rr - wy * 22;
                const int w  = wy * 24 + u;
#pragma unroll
                for (int e = 0; e < 4; ++e) {
                    const int ee = (e + rot) & 3;
                    VT[(d4 + ee) * 200 + w] = vreg[p][ee];
                }
            }
        }
    }
    __syncthreads();   // bar3: VT + Pl ready

    // ---- O = P x V: one 16-d n-tile per wave, K = 192 ----
    f32x4 oacc = (f32x4){0.f, 0.f, 0.f, 0.f};
    __builtin_amdgcn_s_setprio(1);
#pragma unroll
    for (int ks = 0; ks < 6; ++ks) {
        s16x8 ap  = *(const s16x8*)&Pl[ln * 200 + ks * 32 + qq * 8];
        s16x8 bv_ = *(const s16x8*)&VT[(wv * 16 + ln) * 200 + ks * 32 + qq * 8];
        oacc = __builtin_amdgcn_mfma_f32_16x16x32_bf16(ap, bv_, oacc, 0, 0, 0);
    }
    __builtin_amdgcn_s_setprio(0);
    // Ol is private: write immediately, no alias barrier needed
#pragma unroll
    for (int e = 0; e < 4; ++e)
        Ol[(qq * 4 + e) * 72 + wv * 16 + ln] = oacc[e];
    __syncthreads();   // bar4: Ol ready for cross-wave epilogue

    // ---- self-value rejection (bf16 v) + store ----
    {
        const int tt = tid >> 4;       // token 0..15
        const int dl = tid & 15;
        const int tg = y * 48 + x0 + tt;
        const float o0 = Ol[tt * 72 + dl],      o1 = Ol[tt * 72 + dl + 16],
                    o2 = Ol[tt * 72 + dl + 32], o3 = Ol[tt * 72 + dl + 48];
        const short* vs = vbb + (size_t)tg * 64 + dl;
        const float v0 = bs2f(vs[0]),  v1 = bs2f(vs[16]),
                    v2 = bs2f(vs[32]), v3 = bs2f(vs[48]);
        float n2  = v0 * v0 + v1 * v1 + v2 * v2 + v3 * v3;
        float odv = o0 * v0 + o1 * v1 + o2 * v2 + o3 * v3;
#pragma unroll
        for (int off = 1; off < 16; off <<= 1) {
            n2  += __shfl_xor(n2, off);
            odv += __shfl_xor(odv, off);
        }
        const float mxn = fmaxf(sqrtf(n2), 1e-12f);
        const float cf  = odv / (mxn * mxn);
        const int b = bh >> 3, h = bh & 7;
        bf16* dst = ao + ((size_t)b * T_ + tg) * DIM_ + h * 64 + dl;
        dst[0]  = __float2bfloat16(o0 - cf * v0);
        dst[16] = __float2bfloat16(o1 - cf * v1);
        dst[32] = __float2bfloat16(o2 - cf * v2);
        dst[48] = __float2bfloat16(o3 - cf * v3);
    }
}

// ---------------------------------------------------------------------------
extern "C" void kernel_launch(void* const* d_in, const int* in_sizes, int n_in,
                              void* d_out, int out_size, void* d_ws, size_t ws_size,
                              hipStream_t stream)
{
    (void)in_sizes; (void)n_in; (void)out_size; (void)ws_size;

    const float* x  = (const float*)d_in[0];
    const float* wq = (const float*)d_in[1];
    const float* bq = (const float*)d_in[2];
    const float* wk = (const float*)d_in[3];
    const float* bk = (const float*)d_in[4];
    const float* wv = (const float*)d_in[5];
    const float* bv = (const float*)d_in[6];
    const float* wo = (const float*)d_in[7];
    const float* bo = (const float*)d_in[8];
    float* out = (float*)d_out;

    // ws: q,k,v bf16 (3x4.7) + Xt/ao (4.7) + Wb (2.0) = ~21 MB
    const size_t per = (size_t)B_ * HEADS_ * T_ * HD_;   // 2359296
    bf16* qb2 = (bf16*)d_ws;
    bf16* kb2 = qb2 + per;
    bf16* vb2 = kb2 + per;
    bf16* xa  = vb2 + per;            // Xt, later overwritten by ao
    bf16* wb  = xa + per;             // 4 x 512x512 bf16 weights

    prep<<<dim3(512 + 576), 256, 0, stream>>>(x, wq, wk, wv, wo, xa, wb);

    dim3 g1(T_ / 128, 1536 / 128, B_);
    gemm_qkv<<<g1, 256, 0, stream>>>(xa, wb, bq, bk, bv, qb2, kb2, vb2);

    attn_mfma<<<dim3(B_ * HEADS_ * (T_ / 16)), 256, 0, stream>>>(qb2, kb2, vb2, xa);

    dim3 g2(T_ / 64, DIM_ / 64, B_);
    gemm_out<<<g2, 256, 0, stream>>>(xa, wb, bo, out);
}

// Round 27
// 56.209 us; speedup vs baseline: 1.0228x; 1.0228x over previous
//
#include <hip/hip_runtime.h>
#include <hip/hip_bf16.h>
#include <math.h>

typedef __hip_bfloat16 bf16;
typedef __attribute__((ext_vector_type(4))) float f32x4;
typedef __attribute__((ext_vector_type(8))) short s16x8;
typedef __attribute__((ext_vector_type(4))) short s16x4;

#define B_     2
#define DIM_   512
#define Hh     48
#define Ww     48
#define T_     2304
#define HEADS_ 8
#define HD_    64
#define NS_    7
#define R_     3
#define KK_    49

typedef __attribute__((address_space(3))) unsigned       lds_u32_t;
typedef __attribute__((address_space(1))) const unsigned glb_u32_t;

// direct global->LDS DMA, 16B per lane (wave-uniform LDS base + lane*16).
__device__ __forceinline__ void gload16(const short* g, short* l) {
    __builtin_amdgcn_global_load_lds((glb_u32_t*)g, (lds_u32_t*)l, 16, 0, 0);
}

__device__ __forceinline__ short f2bs(float f) {
    bf16 h = __float2bfloat16(f);
    return *(short*)&h;
}

__device__ __forceinline__ float bs2f(short s) {
    bf16 h = *reinterpret_cast<const bf16*>(&s);
    return __bfloat162float(h);
}

// load 8 contiguous fp32, convert to 8 bf16 (as shorts)
__device__ __forceinline__ s16x8 cvt8(const float* __restrict__ p) {
    f32x4 a = *(const f32x4*)p;
    f32x4 b = *(const f32x4*)(p + 4);
    s16x8 r;
    r[0] = f2bs(a[0]); r[1] = f2bs(a[1]); r[2] = f2bs(a[2]); r[3] = f2bs(a[3]);
    r[4] = f2bs(b[0]); r[5] = f2bs(b[1]); r[6] = f2bs(b[2]); r[7] = f2bs(b[3]);
    return r;
}

// ---------------------------------------------------------------------------
// prep: fused weight-convert + X transpose-convert (validated, unchanged).
// ---------------------------------------------------------------------------
__global__ __launch_bounds__(256) void prep(
    const float* __restrict__ x,
    const float* __restrict__ wq, const float* __restrict__ wk,
    const float* __restrict__ wv, const float* __restrict__ wo,
    bf16* __restrict__ xt, bf16* __restrict__ wb)
{
    __shared__ short tile[64 * 72];   // [t][c]
    const int gid = blockIdx.x;
    const int tid = threadIdx.x;

    if (gid < 512) {
        const int i     = gid * 256 + tid;
        const int which = i >> 15;
        const int off   = (i & 32767) * 8;
        const float* src = (which == 0) ? wq : (which == 1) ? wk
                         : (which == 2) ? wv : wo;
        *(s16x8*)((short*)wb + which * 262144 + off) = cvt8(src + off);
        return;
    }

    const int pid = gid - 512;
    const int b   = pid / 288;
    const int rem = pid - b * 288;
    const int t0  = (rem % 36) * 64;
    const int c0  = (rem / 36) * 64;

    const float* X = x + (size_t)b * DIM_ * T_;

    const int c_l = tid >> 4;          // 0..15
    const int t4  = (tid & 15) * 4;    // 0..60
#pragma unroll
    for (int cp = 0; cp < 4; ++cp) {
        const int c = cp * 16 + c_l;
        f32x4 v = *(const f32x4*)(X + (size_t)(c0 + c) * T_ + t0 + t4);
#pragma unroll
        for (int e = 0; e < 4; ++e) tile[(t4 + e) * 72 + c] = f2bs(v[e]);
    }
    __syncthreads();

    const int t_l = tid >> 2;           // 0..63
    const int c16 = (tid & 3) * 16;     // 0,16,32,48
    short* dst = (short*)xt + ((size_t)b * T_ + t0 + t_l) * DIM_ + c0 + c16;
    *(s16x8*)(dst)     = *(const s16x8*)(&tile[t_l * 72 + c16]);
    *(s16x8*)(dst + 8) = *(const s16x8*)(&tile[t_l * 72 + c16 + 8]);
}

// ---------------------------------------------------------------------------
// QKV projection GEMM (measured-best): 128x128 tile, global_load_lds +
// XOR-swizzle staging, BK-128 unroll (4 drains). LDS 64KB.
// ---------------------------------------------------------------------------
__global__ __launch_bounds__(256) void gemm_qkv(
    const bf16* __restrict__ xt, const bf16* __restrict__ wb,
    const float* __restrict__ bq, const float* __restrict__ bk,
    const float* __restrict__ bv,
    bf16* __restrict__ qb2, bf16* __restrict__ kb2, bf16* __restrict__ vb2)
{
    const int tt   = blockIdx.x * 128;
    const int ot   = blockIdx.y * 128;          // [0,1536)
    const int b    = blockIdx.z;
    const int proj = ot >> 9;
    const int orow = ot & 511;                  // {0,128,256,384}
    const int h0   = orow >> 6;                 // head base {0,2,4,6}

    const float* bsel = (proj == 0) ? bq : (proj == 1) ? bk : bv;
    const short* Wb   = (const short*)wb + proj * 262144;
    const short* X    = (const short*)xt + (size_t)b * T_ * DIM_;
    short*       sel  = (short*)((proj == 0) ? qb2 : (proj == 1) ? kb2 : vb2);

    __shared__ __align__(16) short Xs[4][128 * 32];   // 4 k-substeps x 8 KB
    __shared__ __align__(16) short Ws[4][128 * 32];

    const int tid  = threadIdx.x;
    const int lane = tid & 63;
    const int wid  = tid >> 6;
    const int ln   = lane & 15;
    const int qq   = lane >> 4;

    const int swz8 = (((lane & 3) ^ ((lane >> 3) & 3)) * 8);  // write-side
    const int rsw  = (ln >> 1) & 3;                           // read-side XOR

    f32x4 acc[2][8];
#pragma unroll
    for (int r = 0; r < 2; ++r)
#pragma unroll
        for (int n = 0; n < 8; ++n) acc[r][n] = (f32x4){0.f, 0.f, 0.f, 0.f};

    for (int kk = 0; kk < DIM_; kk += 128) {
#pragma unroll
        for (int s = 0; s < 4; ++s) {
#pragma unroll
            for (int half = 0; half < 2; ++half) {
                const int r0 = wid * 32 + half * 16;       // wave-uniform
                const int r  = r0 + (lane >> 2);
                gload16(X  + (size_t)(tt   + r) * DIM_ + kk + s * 32 + swz8, &Xs[s][r0 * 32]);
                gload16(Wb + (size_t)(orow + r) * DIM_ + kk + s * 32 + swz8, &Ws[s][r0 * 32]);
            }
        }
        __syncthreads();

#pragma unroll
        for (int s = 0; s < 4; ++s) {
            s16x8 a[2];
#pragma unroll
            for (int r = 0; r < 2; ++r) {
                const int rr = r * 64 + wid * 16 + ln;
                a[r] = *(const s16x8*)&Xs[s][rr * 32 + ((qq ^ rsw) * 8)];
            }
#pragma unroll
            for (int n = 0; n < 8; ++n) {
                const int rw = n * 16 + ln;
                s16x8 bf = *(const s16x8*)&Ws[s][rw * 32 + ((qq ^ rsw) * 8)];
#pragma unroll
                for (int r = 0; r < 2; ++r)
                    acc[r][n] = __builtin_amdgcn_mfma_f32_16x16x32_bf16(a[r], bf, acc[r][n], 0, 0, 0);
            }
        }
        __syncthreads();
    }

    const size_t tb = (size_t)(b * HEADS_ + h0);
#pragma unroll
    for (int r = 0; r < 2; ++r)
#pragma unroll
        for (int n = 0; n < 8; ++n) {
            const int hn   = n >> 2;
            const int d    = (n & 3) * 16 + ln;
            const float bi = bsel[orow + n * 16 + ln];
#pragma unroll
            for (int e = 0; e < 4; ++e) {
                const int t = tt + r * 64 + wid * 16 + (lane >> 4) * 4 + e;
                sel[((tb + hn) * T_ + t) * HD_ + d] = f2bs(acc[r][n][e] + bi);
            }
        }
}

// ---------------------------------------------------------------------------
// Output projection GEMM (measured-best): 64x64 tile, 576 blocks,
// global_load_lds + XOR-swizzle staging, BK-128 unroll (4 drains). LDS 32KB.
// (BK-256 variant regressed +1.0us: 64KB LDS cut co-residency.)
// ---------------------------------------------------------------------------
__global__ __launch_bounds__(256) void gemm_out(
    const bf16* __restrict__ ao, const bf16* __restrict__ wb,
    const float* __restrict__ bo, float* __restrict__ out)
{
    const int tt = blockIdx.x * 64;
    const int ot = blockIdx.y * 64;
    const int b  = blockIdx.z;

    const short* X  = (const short*)ao + (size_t)b * T_ * DIM_;
    const short* Wb = (const short*)wb + 3 * 262144;

    __shared__ __align__(16) short Ws[4][64 * 32];   // 4 x 4 KB
    __shared__ __align__(16) short Xs[4][64 * 32];   // 4 x 4 KB

    const int tid  = threadIdx.x;
    const int lane = tid & 63;
    const int wid  = tid >> 6;
    const int ln   = lane & 15;
    const int qq   = lane >> 4;

    const int swz8 = (((lane & 3) ^ ((lane >> 3) & 3)) * 8);
    const int rsw  = (ln >> 1) & 3;

    f32x4 acc[4];
#pragma unroll
    for (int n = 0; n < 4; ++n) acc[n] = (f32x4){0.f, 0.f, 0.f, 0.f};

    for (int kk = 0; kk < DIM_; kk += 128) {
#pragma unroll
        for (int s = 0; s < 4; ++s) {
            const int r0 = wid * 16;                  // wave-uniform
            const int r  = r0 + (lane >> 2);
            gload16(Wb + (size_t)(ot + r) * DIM_ + kk + s * 32 + swz8, &Ws[s][r0 * 32]);
            gload16(X  + (size_t)(tt + r) * DIM_ + kk + s * 32 + swz8, &Xs[s][r0 * 32]);
        }
        __syncthreads();

#pragma unroll
        for (int s = 0; s < 4; ++s) {
            s16x8 a = *(const s16x8*)&Ws[s][(wid * 16 + ln) * 32 + ((qq ^ rsw) * 8)];
#pragma unroll
            for (int n = 0; n < 4; ++n) {
                s16x8 bf = *(const s16x8*)&Xs[s][(n * 16 + ln) * 32 + ((qq ^ rsw) * 8)];
                acc[n] = __builtin_amdgcn_mfma_f32_16x16x32_bf16(a, bf, acc[n], 0, 0, 0);
            }
        }
        __syncthreads();
    }

    float* obase = out + (size_t)b * DIM_ * T_;
#pragma unroll
    for (int n = 0; n < 4; ++n) {
        const int t = tt + n * 16 + ln;
#pragma unroll
        for (int e = 0; e < 4; ++e) {
            const int o    = ot + wid * 16 + (lane >> 4) * 4 + e;
            obase[(size_t)o * T_ + t] = acc[n][e] + bo[o];
        }
    }
}

// ---------------------------------------------------------------------------
// MFMA neighborhood attention (measured-best, UNCHANGED): K via
// global_load_lds into unpadded [176][64] Kl with XOR chunk swizzle; Q in
// registers; V reg-staged (T14); T5 setprio; private Ol (4 barriers).
// LDS 36608B, (256,4). grid: 2304 blocks of 256, XCD-swizzled.
// ---------------------------------------------------------------------------
__global__ __launch_bounds__(256, 4) void attn_mfma(
    const bf16* __restrict__ qb2, const bf16* __restrict__ kb2,
    const bf16* __restrict__ vb2, bf16* __restrict__ ao)
{
    __shared__ __align__(16) char smem[36608];
    short* Kl = (short*)smem;                 // [176][64] (stage 0..167)
    short* VT = (short*)smem;                 // [64][200] alias (PV phase)
    short* Pl = (short*)(smem + 25600);       // [16][200]       (private)
    float* Ol = (float*)(smem + 32000);       // [16][72]        (private)

    const int l   = blockIdx.x;
    const int idx = (l & 7) * 288 + (l >> 3);            // XCD-contiguous work
    const int bh  = idx / 144;
    const int rem = idx - bh * 144;
    const int y   = rem / 3;
    const int x0  = (rem % 3) * 16;

    const short* qb  = (const short*)qb2 + (size_t)bh * T_ * HD_;
    const short* kb  = (const short*)kb2 + (size_t)bh * T_ * HD_;
    const short* vbb = (const short*)vb2 + (size_t)bh * T_ * HD_;

    const int tid  = threadIdx.x;
    const int lane = tid & 63;
    const int wv   = tid >> 6;
    const int qq   = lane >> 4;
    const int ln   = lane & 15;

    // ---- zero Pl pads: w in [176,192) (private region, safe pre-bar1) ----
    if (tid < 32) {
        const int t = tid >> 1, c = tid & 1;
        *(s16x8*)&Pl[t * 200 + 176 + c * 8] = (s16x8){0,0,0,0,0,0,0,0};
    }
    // ---- stage K rows via gload16: group g = p*4+wv, rows g*8..g*8+7 ----
    {
        const int swc = (((lane & 7) ^ (lane >> 3)) & 7) * 8;  // global chunk
#pragma unroll
        for (int p = 0; p < 6; ++p) {
            const int g = p * 4 + wv;            // wave-uniform
            if (g < 21) {
                const int r  = g * 8 + (lane >> 3);
                const int wy = r / 24, u = r - wy * 24;
                const int gy = min(max(y + wy - 3, 0), 47);
                const int gx = min(max(x0 + u - 3, 0), 47);
                gload16(kb + (size_t)(gy * 48 + gx) * 64 + swc, &Kl[g * 8 * 64]);
            }
        }
    }
    // ---- Q fragments direct to registers (bitwise = old Ql content) ----
    s16x8 qreg0, qreg1;
    {
        const short* qp = qb + (size_t)(y * 48 + x0 + ln) * 64 + qq * 8;
        qreg0 = *(const s16x8*)(qp);
        qreg1 = *(const s16x8*)(qp + 32);
    }
    // ---- issue V loads to regs (T14: write to LDS after bar2) ----
    s16x4 vreg[10];
    {
        const int rr0 = tid >> 4;          // 0..15
        const int d4  = (tid & 15) * 4;
#pragma unroll
        for (int p = 0; p < 10; ++p) {
            const int rr = p * 16 + rr0;
            if (rr < 154) {
                const int wy = rr / 22, u = rr - wy * 22;
                const int gy = min(max(y + wy - 3, 0), 47);
                const int gx = min(max(x0 + u - 3, 0), 47);
                vreg[p] = *(const s16x4*)(vbb + (size_t)(gy * 48 + gx) * 64 + d4);
            }
        }
    }
    __syncthreads();   // bar1: Kl ready (drains gload_lds via vmcnt)

    // ---- S^T = K x Q^T: 11 m-tiles, 2 k-steps; ALL waves compute all ----
    f32x4 acc[11];
#pragma unroll
    for (int mt = 0; mt < 11; ++mt) acc[mt] = (f32x4){0.f, 0.f, 0.f, 0.f};
    __builtin_amdgcn_s_setprio(1);
#pragma unroll
    for (int ks = 0; ks < 2; ++ks) {
        s16x8 bq_ = (ks == 0) ? qreg0 : qreg1;
#pragma unroll
        for (int mt = 0; mt < 11; ++mt) {
            const int rr = mt * 16 + ln;
            s16x8 ak = *(const s16x8*)&Kl[rr * 64 + (((ks * 4 + qq) ^ (ln & 7)) * 8)];
            acc[mt] = __builtin_amdgcn_mfma_f32_16x16x32_bf16(ak, bq_, acc[mt], 0, 0, 0);
        }
    }
    __builtin_amdgcn_s_setprio(0);

    // ---- mask + wave-local softmax (t = ln; w = mt*16 + qq*4 + e) ----
    const int dx = ln;
    float mxv = -3.0e38f;
#pragma unroll
    for (int mt = 0; mt < 11; ++mt) {
#pragma unroll
        for (int e = 0; e < 4; ++e) {
            const int w  = mt * 16 + qq * 4 + e;
            const int wy = w / 24, u = w - wy * 24;
            const bool valid = (w < 168) &&
                               ((unsigned)(u - dx) <= 6u) &&
                               ((unsigned)(y + wy - 3) < 48u) &&
                               ((unsigned)(x0 + u - 3) < 48u);
            const float s = valid ? acc[mt][e] * 0.125f : -3.0e38f;
            acc[mt][e] = s;
            mxv = fmaxf(mxv, s);
        }
    }
    mxv = fmaxf(mxv, __shfl_xor(mxv, 16));
    mxv = fmaxf(mxv, __shfl_xor(mxv, 32));
    float sum = 0.f;
#pragma unroll
    for (int mt = 0; mt < 11; ++mt)
#pragma unroll
        for (int e = 0; e < 4; ++e) {
            const float p = __expf(acc[mt][e] - mxv);
            acc[mt][e] = p;
            sum += p;
        }
    sum += __shfl_xor(sum, 16);
    sum += __shfl_xor(sum, 32);
    const float inv = 1.0f / sum;

    // ---- write P: compile-time mt, wave-uniform owner (Pl private) ----
#pragma unroll
    for (int mt = 0; mt < 11; ++mt) {
        const int owner = (mt >= 9) ? 3 : (mt / 3);
        if (wv == owner) {
#pragma unroll
            for (int e = 0; e < 4; ++e) {
                const int w = mt * 16 + qq * 4 + e;
                Pl[ln * 200 + w] = f2bs(acc[mt][e] * inv);
            }
        }
    }
    __syncthreads();   // bar2: all Kl reads done -> VT may overwrite

    // ---- zero VT pads + write VT from regs (validated layout) ----
    {
        const int d = tid >> 2, c = tid & 3;
        *(s16x8*)&VT[d * 200 + 168 + c * 8] = (s16x8){0,0,0,0,0,0,0,0};
    }
#pragma unroll
    for (int pp = 0; pp < 2; ++pp) {
        const int r2 = pp * 256 + tid;
        if (r2 < 448) {
            const int wy = r2 >> 6, d = r2 & 63;
            *(unsigned*)&VT[d * 200 + wy * 24 + 22] = 0u;
        }
    }
    {
        const int rr0 = tid >> 4;
        const int d4  = (tid & 15) * 4;
        const int rot = tid & 3;
#pragma unroll
        for (int p = 0; p < 10; ++p) {
            const int rr = p * 16 + rr0;
            if (rr < 154) {
                const int wy = rr / 22, u = rr - wy * 22;
                const int w  = wy * 24 + u;
#pragma unroll
                for (int e = 0; e < 4; ++e) {
                    const int ee = (e + rot) & 3;
                    VT[(d4 + ee) * 200 + w] = vreg[p][ee];
                }
            }
        }
    }
    __syncthreads();   // bar3: VT + Pl ready

    // ---- O = P x V: one 16-d n-tile per wave, K = 192 ----
    f32x4 oacc = (f32x4){0.f, 0.f, 0.f, 0.f};
    __builtin_amdgcn_s_setprio(1);
#pragma unroll
    for (int ks = 0; ks < 6; ++ks) {
        s16x8 ap  = *(const s16x8*)&Pl[ln * 200 + ks * 32 + qq * 8];
        s16x8 bv_ = *(const s16x8*)&VT[(wv * 16 + ln) * 200 + ks * 32 + qq * 8];
        oacc = __builtin_amdgcn_mfma_f32_16x16x32_bf16(ap, bv_, oacc, 0, 0, 0);
    }
    __builtin_amdgcn_s_setprio(0);
    // Ol is private: write immediately, no alias barrier needed
#pragma unroll
    for (int e = 0; e < 4; ++e)
        Ol[(qq * 4 + e) * 72 + wv * 16 + ln] = oacc[e];
    __syncthreads();   // bar4: Ol ready for cross-wave epilogue

    // ---- self-value rejection (bf16 v) + store ----
    {
        const int tt = tid >> 4;       // token 0..15
        const int dl = tid & 15;
        const int tg = y * 48 + x0 + tt;
        const float o0 = Ol[tt * 72 + dl],      o1 = Ol[tt * 72 + dl + 16],
                    o2 = Ol[tt * 72 + dl + 32], o3 = Ol[tt * 72 + dl + 48];
        const short* vs = vbb + (size_t)tg * 64 + dl;
        const float v0 = bs2f(vs[0]),  v1 = bs2f(vs[16]),
                    v2 = bs2f(vs[32]), v3 = bs2f(vs[48]);
        float n2  = v0 * v0 + v1 * v1 + v2 * v2 + v3 * v3;
        float odv = o0 * v0 + o1 * v1 + o2 * v2 + o3 * v3;
#pragma unroll
        for (int off = 1; off < 16; off <<= 1) {
            n2  += __shfl_xor(n2, off);
            odv += __shfl_xor(odv, off);
        }
        const float mxn = fmaxf(sqrtf(n2), 1e-12f);
        const float cf  = odv / (mxn * mxn);
        const int b = bh >> 3, h = bh & 7;
        bf16* dst = ao + ((size_t)b * T_ + tg) * DIM_ + h * 64 + dl;
        dst[0]  = __float2bfloat16(o0 - cf * v0);
        dst[16] = __float2bfloat16(o1 - cf * v1);
        dst[32] = __float2bfloat16(o2 - cf * v2);
        dst[48] = __float2bfloat16(o3 - cf * v3);
    }
}

// ---------------------------------------------------------------------------
extern "C" void kernel_launch(void* const* d_in, const int* in_sizes, int n_in,
                              void* d_out, int out_size, void* d_ws, size_t ws_size,
                              hipStream_t stream)
{
    (void)in_sizes; (void)n_in; (void)out_size; (void)ws_size;

    const float* x  = (const float*)d_in[0];
    const float* wq = (const float*)d_in[1];
    const float* bq = (const float*)d_in[2];
    const float* wk = (const float*)d_in[3];
    const float* bk = (const float*)d_in[4];
    const float* wv = (const float*)d_in[5];
    const float* bv = (const float*)d_in[6];
    const float* wo = (const float*)d_in[7];
    const float* bo = (const float*)d_in[8];
    float* out = (float*)d_out;

    // ws: q,k,v bf16 (3x4.7) + Xt/ao (4.7) + Wb (2.0) = ~21 MB
    const size_t per = (size_t)B_ * HEADS_ * T_ * HD_;   // 2359296
    bf16* qb2 = (bf16*)d_ws;
    bf16* kb2 = qb2 + per;
    bf16* vb2 = kb2 + per;
    bf16* xa  = vb2 + per;            // Xt, later overwritten by ao
    bf16* wb  = xa + per;             // 4 x 512x512 bf16 weights

    prep<<<dim3(512 + 576), 256, 0, stream>>>(x, wq, wk, wv, wo, xa, wb);

    dim3 g1(T_ / 128, 1536 / 128, B_);
    gemm_qkv<<<g1, 256, 0, stream>>>(xa, wb, bq, bk, bv, qb2, kb2, vb2);

    attn_mfma<<<dim3(B_ * HEADS_ * (T_ / 16)), 256, 0, stream>>>(qb2, kb2, vb2, xa);

    dim3 g2(T_ / 64, DIM_ / 64, B_);
    gemm_out<<<g2, 256, 0, stream>>>(xa, wb, bo, out);
}